// Round 11
// baseline (69.548 us; speedup 1.0000x reference)
//
#include <hip/hip_runtime.h>

#define CD_B 4
#define CD_N 4096
#define CD_TOTAL (CD_B * CD_N)   // 16384 points per array
#define TILE 256

typedef float v2f __attribute__((ext_vector_type(2)));

// ---------------- Kernel A: tiled partial mins (the heavy kernel) ----------
// Grid: 4 batches x 16 own-tiles x 16 stream-tiles = 1024 blocks, 256 thr.
// LDS tiles in SoA (xs/ys/zs/norm) so the streamed side reads ds_read_b64
// pairs {j, j+1} directly into aligned VGPR pairs; inner loop is float2
// ext-vector math -> v_pk_fma_f32 / v_pk_min_f32 (packed fp32, 2 FLOP-pairs
// per instr). dist via |p-g|^2 = |p|^2 + (|g|^2 - 2 p.g).
// Lane owns 4 points (4 independent packed min chains); the 4 waves split the
// streamed 256 into 64 each; partials combine via LDS; plain stores to pm.
// pm layout: [dir][b][own_tile][stream_tile][256]
__global__ __launch_bounds__(256, 4) void cd_tiles(const float* __restrict__ recon,
                                                   const float* __restrict__ gt,
                                                   float* __restrict__ pm,
                                                   float* __restrict__ out) {
    const int bid = blockIdx.x;
    const int b   = bid >> 8;
    const int ti  = (bid >> 4) & 15;
    const int tj  = bid & 15;
    const int t   = threadIdx.x;
    const int w   = t >> 6;   // wave 0..3
    const int l   = t & 63;   // lane

    if (bid == 0 && t == 0) out[0] = 0.f;   // kernel B accumulates after us

    __shared__ alignas(16) float rxs[TILE], rys[TILE], rzs[TILE], rns[TILE];
    __shared__ alignas(16) float gxs[TILE], gys[TILE], gzs[TILE], gns[TILE];
    __shared__ float part[4][TILE];

    {   // Stage: thread t loads point t of each tile, computes its norm (SoA).
        const float* rp = recon + ((size_t)(b * CD_N + ti * TILE) + t) * 3;
        const float* gp = gt    + ((size_t)(b * CD_N + tj * TILE) + t) * 3;
        const float rx = rp[0], ry = rp[1], rz = rp[2];
        const float gx = gp[0], gy = gp[1], gz = gp[2];
        rxs[t] = rx; rys[t] = ry; rzs[t] = rz;
        rns[t] = fmaf(rz, rz, fmaf(ry, ry, rx * rx));
        gxs[t] = gx; gys[t] = gy; gzs[t] = gz;
        gns[t] = fmaf(gz, gz, fmaf(gy, gy, gx * gx));
    }
    __syncthreads();

    const float INF = __builtin_inff();

    // ---- Phase 1 (dir 0): rowmin. Lane l owns recon rows {l,64+l,128+l,192+l};
    //      wave w streams gt cols [64w, 64w+64) as float2 pairs.
    {
        const v2f a0x = -2.f * rxs[l],       a0y = -2.f * rys[l],       a0z = -2.f * rzs[l];
        const v2f a1x = -2.f * rxs[64 + l],  a1y = -2.f * rys[64 + l],  a1z = -2.f * rzs[64 + l];
        const v2f a2x = -2.f * rxs[128 + l], a2y = -2.f * rys[128 + l], a2z = -2.f * rzs[128 + l];
        const v2f a3x = -2.f * rxs[192 + l], a3y = -2.f * rys[192 + l], a3z = -2.f * rzs[192 + l];
        v2f m0 = INF, m1 = INF, m2 = INF, m3 = INF;
        const int jbase = w << 6;
        #pragma unroll 8
        for (int jj = 0; jj < 64; jj += 2) {
            const int j = jbase + jj;
            const v2f gx = *(const v2f*)&gxs[j];   // broadcast ds_read_b64
            const v2f gy = *(const v2f*)&gys[j];
            const v2f gz = *(const v2f*)&gzs[j];
            const v2f gn = *(const v2f*)&gns[j];
            v2f d;
            d = __builtin_elementwise_fma(a0z, gz, gn);
            d = __builtin_elementwise_fma(a0y, gy, d);
            d = __builtin_elementwise_fma(a0x, gx, d);
            m0 = __builtin_elementwise_min(m0, d);
            d = __builtin_elementwise_fma(a1z, gz, gn);
            d = __builtin_elementwise_fma(a1y, gy, d);
            d = __builtin_elementwise_fma(a1x, gx, d);
            m1 = __builtin_elementwise_min(m1, d);
            d = __builtin_elementwise_fma(a2z, gz, gn);
            d = __builtin_elementwise_fma(a2y, gy, d);
            d = __builtin_elementwise_fma(a2x, gx, d);
            m2 = __builtin_elementwise_min(m2, d);
            d = __builtin_elementwise_fma(a3z, gz, gn);
            d = __builtin_elementwise_fma(a3y, gy, d);
            d = __builtin_elementwise_fma(a3x, gx, d);
            m3 = __builtin_elementwise_min(m3, d);
        }
        part[w][l]       = fminf(m0[0], m0[1]);
        part[w][64 + l]  = fminf(m1[0], m1[1]);
        part[w][128 + l] = fminf(m2[0], m2[1]);
        part[w][192 + l] = fminf(m3[0], m3[1]);
    }
    __syncthreads();
    {   // combine wave partials for recon point t; add |p|^2; plain store
        const float v = fminf(fminf(part[0][t], part[1][t]),
                              fminf(part[2][t], part[3][t]));
        const float dist = fmaxf(v + rns[t], 0.f);
        pm[(((b << 4) + ti) << 12) + (tj << 8) + t] = dist;
    }
    __syncthreads();  // part[] reused below

    // ---- Phase 2 (dir 1): colmin. Lane l owns gt cols; wave w streams recon.
    {
        const v2f a0x = -2.f * gxs[l],       a0y = -2.f * gys[l],       a0z = -2.f * gzs[l];
        const v2f a1x = -2.f * gxs[64 + l],  a1y = -2.f * gys[64 + l],  a1z = -2.f * gzs[64 + l];
        const v2f a2x = -2.f * gxs[128 + l], a2y = -2.f * gys[128 + l], a2z = -2.f * gzs[128 + l];
        const v2f a3x = -2.f * gxs[192 + l], a3y = -2.f * gys[192 + l], a3z = -2.f * gzs[192 + l];
        v2f m0 = INF, m1 = INF, m2 = INF, m3 = INF;
        const int ibase = w << 6;
        #pragma unroll 8
        for (int ii = 0; ii < 64; ii += 2) {
            const int i = ibase + ii;
            const v2f rx = *(const v2f*)&rxs[i];
            const v2f ry = *(const v2f*)&rys[i];
            const v2f rz = *(const v2f*)&rzs[i];
            const v2f rn = *(const v2f*)&rns[i];
            v2f d;
            d = __builtin_elementwise_fma(a0z, rz, rn);
            d = __builtin_elementwise_fma(a0y, ry, d);
            d = __builtin_elementwise_fma(a0x, rx, d);
            m0 = __builtin_elementwise_min(m0, d);
            d = __builtin_elementwise_fma(a1z, rz, rn);
            d = __builtin_elementwise_fma(a1y, ry, d);
            d = __builtin_elementwise_fma(a1x, rx, d);
            m1 = __builtin_elementwise_min(m1, d);
            d = __builtin_elementwise_fma(a2z, rz, rn);
            d = __builtin_elementwise_fma(a2y, ry, d);
            d = __builtin_elementwise_fma(a2x, rx, d);
            m2 = __builtin_elementwise_min(m2, d);
            d = __builtin_elementwise_fma(a3z, rz, rn);
            d = __builtin_elementwise_fma(a3y, ry, d);
            d = __builtin_elementwise_fma(a3x, rx, d);
            m3 = __builtin_elementwise_min(m3, d);
        }
        part[w][l]       = fminf(m0[0], m0[1]);
        part[w][64 + l]  = fminf(m1[0], m1[1]);
        part[w][128 + l] = fminf(m2[0], m2[1]);
        part[w][192 + l] = fminf(m3[0], m3[1]);
    }
    __syncthreads();
    {   // combine wave partials for gt point t; add |g|^2; plain store
        const float v = fminf(fminf(part[0][t], part[1][t]),
                              fminf(part[2][t], part[3][t]));
        const float dist = fmaxf(v + gns[t], 0.f);
        pm[262144 + (((b << 4) + tj) << 12) + (ti << 8) + t] = dist;
    }
}

// ---------------- Kernel B: gather 16 partials per point, sum, accumulate ---
// 128 blocks x 256 threads = 32768 threads, one per (dir, b, own_tile, p).
__global__ __launch_bounds__(256) void cd_gather(const float* __restrict__ pm,
                                                 float* __restrict__ out) {
    const int tid = blockIdx.x * 256 + threadIdx.x;  // [0, 32768)
    const int p   = tid & 255;
    const int ot  = (tid >> 8) & 15;
    const int gb  = tid >> 12;                       // dir*4 + b, [0,8)
    const float* base = pm + ((((gb << 4) + ot) << 4) << 8) + p;

    float m = base[0];
    #pragma unroll
    for (int st = 1; st < 16; ++st) m = fminf(m, base[st << 8]);

    for (int off = 32; off; off >>= 1) m += __shfl_down(m, off);
    __shared__ float ws[4];
    const int t = threadIdx.x;
    if ((t & 63) == 0) ws[t >> 6] = m;
    __syncthreads();
    if (t == 0) {
        const float s = ws[0] + ws[1] + ws[2] + ws[3];
        atomicAdd(out, s * (0.5f / (float)CD_TOTAL));  // (mean1+mean2)/2
    }
}

extern "C" void kernel_launch(void* const* d_in, const int* in_sizes, int n_in,
                              void* d_out, int out_size, void* d_ws, size_t ws_size,
                              hipStream_t stream) {
    const float* recon = (const float*)d_in[0];
    const float* gt    = (const float*)d_in[1];
    float* pm  = (float*)d_ws;     // 2*4*16*16*256 floats = 2 MB
    float* out = (float*)d_out;

    cd_tiles<<<CD_B * 16 * 16, 256, 0, stream>>>(recon, gt, pm, out);
    cd_gather<<<128, 256, 0, stream>>>(pm, out);
}